// Round 13
// baseline (371.059 us; speedup 1.0000x reference)
//
#include <hip/hip_runtime.h>
#include <hip/hip_bf16.h>
#include <stdint.h>

typedef __bf16 bf16_t;
typedef __bf16 bf16x4 __attribute__((ext_vector_type(4)));
typedef __bf16 bf16x8 __attribute__((ext_vector_type(8)));
typedef float  f32x4  __attribute__((ext_vector_type(4)));

#define B_   4
#define S_   2048
#define D_   1024
#define H_   16
#define DH_  64
#define MTOT (B_ * S_)   // 8192
#define NITEMS 1024      // 16 qb x 64 bh
#define NPERS  768       // persistent blocks = 256 CU x 3

// ---------------------------------------------------------------- utilities
__device__ __forceinline__ void gload_lds16(const void* g, void* l) {
  // direct global->LDS, 16B per lane; LDS dest = wave-uniform base + lane*16
  __builtin_amdgcn_global_load_lds((const __attribute__((address_space(1))) void*)g,
                                   (__attribute__((address_space(3))) void*)l,
                                   16, 0, 0);
}

// ---------------------------------------------------------------- fp32 -> bf16 convert
__global__ __launch_bounds__(256) void k_cvt(const float* __restrict__ in,
                                             bf16_t* __restrict__ out, int n8) {
  for (int i = blockIdx.x * blockDim.x + threadIdx.x; i < n8;
       i += gridDim.x * blockDim.x) {
    const float4* p = (const float4*)(in + (size_t)i * 8);
    float4 a = p[0], b = p[1];
    bf16x8 o;
    o[0] = (bf16_t)a.x; o[1] = (bf16_t)a.y; o[2] = (bf16_t)a.z; o[3] = (bf16_t)a.w;
    o[4] = (bf16_t)b.x; o[5] = (bf16_t)b.y; o[6] = (bf16_t)b.z; o[7] = (bf16_t)b.w;
    *(bf16x8*)(out + (size_t)i * 8) = o;
  }
}

// ---------------------------------------------------------------- pack Wq/Wk/Wv -> Wt[3][1024][1024] (B^T layout, bf16)
// Wt[z][h*64+kk][d] = W_z[h][d][kk]  (Wq scaled by 1/sqrt(DH)=0.125)
__global__ __launch_bounds__(256) void k_pack(const float* __restrict__ Wq,
                                              const float* __restrict__ Wk,
                                              const float* __restrict__ Wv,
                                              bf16_t* __restrict__ Wt) {
  const int z = blockIdx.z;
  const float* W = (z == 0) ? Wq : ((z == 1) ? Wk : Wv);
  const float scale = (z == 0) ? 0.125f : 1.0f;
  const int h  = blockIdx.y;
  const int d0 = blockIdx.x * 64;

  __shared__ float tile[64][65];   // [d_local][kk]
  const int t  = threadIdx.x;
  const int r  = t >> 2;           // 0..63
  const int c0 = (t & 3) * 16;     // 0,16,32,48

  const float* src = W + ((size_t)h * D_ + d0 + r) * DH_ + c0;
#pragma unroll
  for (int j4 = 0; j4 < 4; ++j4) {
    float4 v = *(const float4*)(src + j4 * 4);
    tile[r][c0 + j4 * 4 + 0] = v.x;
    tile[r][c0 + j4 * 4 + 1] = v.y;
    tile[r][c0 + j4 * 4 + 2] = v.z;
    tile[r][c0 + j4 * 4 + 3] = v.w;
  }
  __syncthreads();

  const int kk = r, dd0 = c0;
  bf16_t* dst = Wt + ((size_t)z * D_ + h * DH_ + kk) * D_ + d0 + dd0;
  bf16x8 o0, o1;
#pragma unroll
  for (int j = 0; j < 8; ++j) {
    o0[j] = (bf16_t)(tile[dd0 + j][kk] * scale);
    o1[j] = (bf16_t)(tile[dd0 + 8 + j][kk] * scale);
  }
  *(bf16x8*)(dst)     = o0;
  *(bf16x8*)(dst + 8) = o1;
}

// ---------------------------------------------------------------- V^T: Vp[b][s][h*64+d] -> VpT[(b*16+h)*64+d][s]
__global__ __launch_bounds__(256) void k_vt(const bf16_t* __restrict__ Vp,
                                            bf16_t* __restrict__ VpT) {
  __shared__ bf16_t tile[64][72];   // [s_local][d], pad 8
  const int bh = blockIdx.y;
  const int b  = bh >> 4, h = bh & 15;
  const int s0 = blockIdx.x * 64;
  const int t  = threadIdx.x;
  const int r  = t >> 2;            // 0..63
  const int c0 = (t & 3) * 16;      // 0,16,32,48

  const bf16_t* src = Vp + ((size_t)(b * S_ + s0 + r)) * D_ + h * DH_ + c0;
  *(bf16x8*)&tile[r][c0]     = *(const bf16x8*)(src);
  *(bf16x8*)&tile[r][c0 + 8] = *(const bf16x8*)(src + 8);
  __syncthreads();

  // write: d = r, s range c0..c0+16
  bf16x8 o0, o1;
#pragma unroll
  for (int j = 0; j < 8; ++j) {
    o0[j] = tile[c0 + j][r];
    o1[j] = tile[c0 + 8 + j][r];
  }
  bf16_t* dst = VpT + ((size_t)(bh * DH_ + r)) * S_ + s0 + c0;
  *(bf16x8*)dst       = o0;
  *(bf16x8*)(dst + 8) = o1;
}

// ---------------------------------------------------------------- GEMM  C[M,N] = A[M,K] * B[N,K]^T
// m97 structure: 128x128 tile, BK=32, 4 waves (2x2), 4x4 16x16x32 frags/wave.
// MODE 0: z-indexed (3 projections), bf16 out.  MODE 1: fp32 out + bias.
template <int MODE>
__global__ __launch_bounds__(256) void k_gemm(
    const bf16_t* __restrict__ A0, const bf16_t* __restrict__ A1,
    const bf16_t* __restrict__ A2, const bf16_t* __restrict__ W,
    bf16_t* __restrict__ O0, bf16_t* __restrict__ O1, bf16_t* __restrict__ O2,
    float* __restrict__ OF, const float* __restrict__ bias,
    int M, int N, int K) {
  const int z = blockIdx.z;
  const bf16_t* A  = (MODE == 0) ? (z == 0 ? A0 : (z == 1 ? A1 : A2)) : A0;
  const bf16_t* Bt = (MODE == 0) ? (W + (size_t)z * N * K) : W;
  bf16_t* OB = (MODE == 0) ? (z == 0 ? O0 : (z == 1 ? O1 : O2)) : nullptr;

  __shared__ bf16_t As[128 * 32];
  __shared__ bf16_t Bs[128 * 32];

  const int tid  = threadIdx.x;
  const int w    = tid >> 6, lane = tid & 63;
  const int wm   = w >> 1,   wn   = w & 1;
  const int g    = lane >> 4, cl  = lane & 15;
  const int m0   = blockIdx.x * 128, n0 = blockIdx.y * 128;
  const int r_a  = lane >> 2;            // row within chunk-group
  const int c_a  = (lane & 3) * 8;       // col (elements)

  f32x4 acc[4][4] = {};

  for (int k0 = 0; k0 < K; k0 += 32) {
#pragma unroll
    for (int it = 0; it < 2; ++it) {
      const int c16 = it * 4 + w;                 // wave-uniform chunk id
      const int row = c16 * 16 + r_a;
      gload_lds16(A  + (size_t)(m0 + row) * K + (k0 + c_a),
                  (bf16_t*)((char*)As + c16 * 1024));
      gload_lds16(Bt + (size_t)(n0 + row) * K + (k0 + c_a),
                  (bf16_t*)((char*)Bs + c16 * 1024));
    }
    __syncthreads();

    bf16x8 af[4], bfv[4];
#pragma unroll
    for (int mi = 0; mi < 4; ++mi)
      af[mi] = *(const bf16x8*)&As[(wm * 64 + mi * 16 + cl) * 32 + g * 8];
#pragma unroll
    for (int ni = 0; ni < 4; ++ni)
      bfv[ni] = *(const bf16x8*)&Bs[(wn * 64 + ni * 16 + cl) * 32 + g * 8];
#pragma unroll
    for (int mi = 0; mi < 4; ++mi)
#pragma unroll
      for (int ni = 0; ni < 4; ++ni)
        acc[mi][ni] = __builtin_amdgcn_mfma_f32_16x16x32_bf16(
            af[mi], bfv[ni], acc[mi][ni], 0, 0, 0);
    __syncthreads();
  }

  // epilogue: C/D layout col = lane&15, row = (lane>>4)*4 + i  [m89-verified]
#pragma unroll
  for (int mi = 0; mi < 4; ++mi) {
#pragma unroll
    for (int ni = 0; ni < 4; ++ni) {
      const int col = n0 + wn * 64 + ni * 16 + cl;
#pragma unroll
      for (int i = 0; i < 4; ++i) {
        const int row = m0 + wm * 64 + mi * 16 + g * 4 + i;
        if (MODE == 0)
          OB[(size_t)row * N + col] = (bf16_t)acc[mi][ni][i];
        else
          OF[(size_t)row * N + col] = acc[mi][ni][i] + bias[col];
      }
    }
  }
}

// ---------------------------------------------------------------- causal flash attention (v5)
// Persistent work-queue (NPERS blocks), items (qb, bh) longest-first.
// Wave w owns q rows [qb*128+32w, +32). KV tiles of 64.
// v5: K and V^T (pre-transposed by k_vt) both staged via gload_lds with
//     pre-swizzled global source (XOR (row&7)<<4), double-buffered, ONE
//     barrier per tile. Swapped QK^T lane-local softmax (v4, measured).
__global__ __launch_bounds__(256, 3) void k_attn(const bf16_t* __restrict__ Qp,
                                                 const bf16_t* __restrict__ Kp,
                                                 const bf16_t* __restrict__ VpT,
                                                 bf16_t* __restrict__ AO,
                                                 int* __restrict__ wq_ctr,
                                                 const int* __restrict__ causal_p) {
  __shared__ bf16_t Ks[2 * 64 * 64];   // swizzled K tiles [kv][d] (linear dest)
  __shared__ bf16_t Vt[2 * 64 * 64];   // swizzled V^T tiles [d][kv]
  __shared__ bf16_t Pb[4][32 * 72];    // per-wave P [q_local 32][kv 64], pad 8
  __shared__ int s_item;

  const int tid  = threadIdx.x;
  const int w    = tid >> 6, lane = tid & 63;
  const int g    = lane >> 4, cl  = lane & 15;
  const int causal = *causal_p;
  const int gbase = (lane & 48) | ((lane & 48) >> 2);   // srcLane: own g-group, cl=g*4
  const int swz   = (cl & 7) << 4;                      // read-side XOR (bytes)
  const int srow  = lane >> 3;                          // stage: row within 8-row chunk
  const int scb   = ((lane & 7) * 16) ^ (srow << 4);    // stage: pre-swizzled col byte

  for (;;) {
    if (tid == 0) s_item = atomicAdd(wq_ctr, 1);
    __syncthreads();                 // publish s_item
    const int item = s_item;
    if (item >= NITEMS) break;

    const int qb = 15 - (item >> 6);       // longest first
    const int bh = item & 63;
    const int b  = bh >> 4, h = bh & 15;
    const int q0 = qb * 128;
    const int nt = causal ? (2 * qb + 2) : (S_ >> 6);
    const int base_q = q0 + w * 32;
    const size_t base = ((size_t)b * S_) * D_ + (size_t)h * DH_;
    const bf16_t* Vth = VpT + (size_t)bh * DH_ * S_;    // [64 d][2048 s]

    // Q fragments held in registers for the whole item
    bf16x8 aq[2][2];
#pragma unroll
    for (int qi = 0; qi < 2; ++qi)
#pragma unroll
      for (int ks = 0; ks < 2; ++ks)
        aq[qi][ks] = *(const bf16x8*)(Qp + base + (size_t)(base_q + qi * 16 + cl) * D_ +
                                      ks * 32 + g * 8);

    f32x4 acc_o[2][4] = {};
    float m_run[2], l_run[2];
#pragma unroll
    for (int qi = 0; qi < 2; ++qi) { m_run[qi] = -1e30f; l_run[qi] = 0.f; }

    // ---- stage tile 0 into buf 0 (K rows=kv from Kp; V^T rows=d from Vth) ----
#pragma unroll
    for (int it = 0; it < 2; ++it) {
      const int c16 = it * 4 + w;
      const int row = c16 * 8 + srow;
      gload_lds16((const char*)(Kp + base + (size_t)row * D_) + scb,
                  (char*)Ks + c16 * 1024);
      gload_lds16((const char*)(Vth + (size_t)row * S_) + scb,
                  (char*)Vt + c16 * 1024);
    }
    __syncthreads();

    for (int t = 0; t < nt; ++t) {
      const int kv0 = t * 64;
      const int buf = t & 1;
      const bool pf = (t + 1 < nt);

      // ---- prefetch tile t+1 into buf^1 (in flight across this tile) ----
      if (pf) {
        const int kvn = kv0 + 64;
#pragma unroll
        for (int it = 0; it < 2; ++it) {
          const int c16 = it * 4 + w;
          const int row = c16 * 8 + srow;
          gload_lds16((const char*)(Kp + base + (size_t)(kvn + row) * D_) + scb,
                      (char*)Ks + (buf ^ 1) * 8192 + c16 * 1024);
          gload_lds16((const char*)(Vth + (size_t)row * S_ + kvn) + scb,
                      (char*)Vt + (buf ^ 1) * 8192 + c16 * 1024);
        }
      }

      const bool active    = (!causal) || (kv0 <= base_q + 31);
      const bool need_mask = causal && (kv0 + 63 > base_q);

      if (active) {
        const char* ksb = (const char*)Ks + buf * 8192;
        const char* vtb = (const char*)Vt + buf * 8192;

        // ---- swapped QK^T: lane holds q=cl, kv=c*16+g*4+i ----
        f32x4 sc[2][4];
#pragma unroll
        for (int qi = 0; qi < 2; ++qi)
#pragma unroll
          for (int c = 0; c < 4; ++c) sc[qi][c] = (f32x4){0.f, 0.f, 0.f, 0.f};

        __builtin_amdgcn_s_setprio(1);
#pragma unroll
        for (int c = 0; c < 4; ++c) {
          bf16x8 kf0 = *(const bf16x8*)(ksb + (c * 16 + cl) * 128 + ((g * 16) ^ swz));
          bf16x8 kf1 = *(const bf16x8*)(ksb + (c * 16 + cl) * 128 + ((64 + g * 16) ^ swz));
#pragma unroll
          for (int qi = 0; qi < 2; ++qi) {
            sc[qi][c] = __builtin_amdgcn_mfma_f32_16x16x32_bf16(kf0, aq[qi][0], sc[qi][c], 0, 0, 0);
            sc[qi][c] = __builtin_amdgcn_mfma_f32_16x16x32_bf16(kf1, aq[qi][1], sc[qi][c], 0, 0, 0);
          }
        }
        __builtin_amdgcn_s_setprio(0);

        // ---- causal mask (q=cl, kv=c*16+g*4+i) ----
        if (need_mask) {
#pragma unroll
          for (int qi = 0; qi < 2; ++qi) {
            const int qg = base_q + qi * 16 + cl;
#pragma unroll
            for (int c = 0; c < 4; ++c)
#pragma unroll
              for (int i = 0; i < 4; ++i) {
                const int kg = kv0 + c * 16 + g * 4 + i;
                if (kg > qg) sc[qi][c][i] = -1e30f;
              }
          }
        }

        // ---- lane-local online softmax + packed P write ----
#pragma unroll
        for (int qi = 0; qi < 2; ++qi) {
          float m4[4];
#pragma unroll
          for (int c = 0; c < 4; ++c)
            m4[c] = fmaxf(fmaxf(sc[qi][c][0], sc[qi][c][1]),
                          fmaxf(sc[qi][c][2], sc[qi][c][3]));
          float m1 = fmaxf(fmaxf(m4[0], m4[1]), fmaxf(m4[2], m4[3]));
          m1 = fmaxf(m1, __shfl_xor(m1, 16));
          m1 = fmaxf(m1, __shfl_xor(m1, 32));
          if (!__all(m1 <= m_run[qi] + 8.0f)) {      // defer-max THR=8 (T13)
            const float mnew = fmaxf(m_run[qi], m1);
            const float alpha = exp2f((m_run[qi] - mnew) * 1.44269504f);
            m_run[qi] = mnew;
            l_run[qi] *= alpha;
#pragma unroll
            for (int i = 0; i < 4; ++i) {            // broadcast alpha to O-row domain
              const float ai = __shfl(alpha, gbase + i);
              acc_o[qi][0][i] *= ai;
              acc_o[qi][1][i] *= ai;
              acc_o[qi][2][i] *= ai;
              acc_o[qi][3][i] *= ai;
            }
          }
          float s = 0.f;
#pragma unroll
          for (int c = 0; c < 4; ++c) {
            bf16x4 pv;
#pragma unroll
            for (int i = 0; i < 4; ++i) {
              const float p = exp2f((sc[qi][c][i] - m_run[qi]) * 1.44269504f);
              s += p;
              pv[i] = (bf16_t)p;
            }
            *(bf16x4*)&Pb[w][(qi * 16 + cl) * 72 + c * 16 + ((lane >> 2) & 12)] = pv;
          }
          s += __shfl_xor(s, 16);
          s += __shfl_xor(s, 32);
          l_run[qi] += s;
        }

        // ---- PV: O[32 q][64 d] += P * V  (same-wave Pb RAW, lgkmcnt-ordered) ----
        __builtin_amdgcn_s_setprio(1);
#pragma unroll
        for (int ks = 0; ks < 2; ++ks) {
          bf16x8 pa0 = *(const bf16x8*)&Pb[w][(cl) * 72 + ks * 32 + g * 8];
          bf16x8 pa1 = *(const bf16x8*)&Pb[w][(16 + cl) * 72 + ks * 32 + g * 8];
#pragma unroll
          for (int dg = 0; dg < 4; ++dg) {
            bf16x8 vf = *(const bf16x8*)(vtb + (dg * 16 + cl) * 128 +
                                         ((ks * 64 + g * 16) ^ swz));
            acc_o[0][dg] = __builtin_amdgcn_mfma_f32_16x16x32_bf16(pa0, vf, acc_o[0][dg], 0, 0, 0);
            acc_o[1][dg] = __builtin_amdgcn_mfma_f32_16x16x32_bf16(pa1, vf, acc_o[1][dg], 0, 0, 0);
          }
        }
        __builtin_amdgcn_s_setprio(0);
      }

      __syncthreads();   // tile advance: prefetch vmcnt drained; all reads of buf done
    }

    // ---- normalize + write AO[b, q, h*64 + d] (bf16) ----
#pragma unroll
    for (int qi = 0; qi < 2; ++qi) {
      float lq[4];
#pragma unroll
      for (int i = 0; i < 4; ++i) lq[i] = __shfl(l_run[qi], gbase + i);
#pragma unroll
      for (int dg = 0; dg < 4; ++dg)
#pragma unroll
        for (int i = 0; i < 4; ++i) {
          const int q = base_q + qi * 16 + g * 4 + i;
          AO[base + (size_t)q * D_ + dg * 16 + cl] = (bf16_t)(acc_o[qi][dg][i] / lq[i]);
        }
    }
  }
}

// ---------------------------------------------------------------- launch
extern "C" void kernel_launch(void* const* d_in, const int* in_sizes, int n_in,
                              void* d_out, int out_size, void* d_ws, size_t ws_size,
                              hipStream_t stream) {
  const float* query = (const float*)d_in[0];
  const float* key_  = (const float*)d_in[1];
  const float* value = (const float*)d_in[2];
  const float* Wq    = (const float*)d_in[3];
  const float* Wk    = (const float*)d_in[4];
  const float* Wv    = (const float*)d_in[5];
  const float* Wo    = (const float*)d_in[6];
  const float* bo    = (const float*)d_in[7];
  const int*   causal = (const int*)d_in[8];
  float* out = (float*)d_out;

  char* ws = (char*)d_ws;
  size_t off = 0;
  auto alloc = [&](size_t bytes) {
    char* p = ws + off;
    off += (bytes + 255) & ~(size_t)255;
    return p;
  };
  const size_t TB = (size_t)MTOT * D_ * sizeof(bf16_t);   // 16 MiB
  bf16_t* qin = (bf16_t*)alloc(TB);    // reused as AO after projections
  bf16_t* kin = (bf16_t*)alloc(TB);
  bf16_t* vin = (bf16_t*)alloc(TB);
  bf16_t* Qp  = (bf16_t*)alloc(TB);
  bf16_t* Kp  = (bf16_t*)alloc(TB);
  bf16_t* Vp  = (bf16_t*)alloc(TB);
  bf16_t* VpT = (bf16_t*)alloc(TB);
  bf16_t* wt  = (bf16_t*)alloc((size_t)3 * D_ * D_ * sizeof(bf16_t));
  bf16_t* wob = (bf16_t*)alloc((size_t)D_ * D_ * sizeof(bf16_t));
  int*    ctr = (int*)alloc(256);
  bf16_t* ao  = qin;   // qin dead after projection GEMM

  hipMemsetAsync(ctr, 0, sizeof(int), stream);

  const int n8 = MTOT * D_ / 8;
  k_cvt<<<2048, 256, 0, stream>>>(query, qin, n8);
  k_cvt<<<2048, 256, 0, stream>>>(key_,  kin, n8);
  k_cvt<<<2048, 256, 0, stream>>>(value, vin, n8);
  k_cvt<<<512, 256, 0, stream>>>(Wo, wob, D_ * D_ / 8);
  k_pack<<<dim3(16, 16, 3), 256, 0, stream>>>(Wq, Wk, Wv, wt);

  k_gemm<0><<<dim3(MTOT / 128, D_ / 128, 3), 256, 0, stream>>>(
      qin, kin, vin, wt, Qp, Kp, Vp, nullptr, nullptr, MTOT, D_, D_);

  k_vt<<<dim3(S_ / 64, B_ * H_), 256, 0, stream>>>(Vp, VpT);

  k_attn<<<dim3(NPERS, 1), 256, 0, stream>>>(Qp, Kp, VpT, ao, ctr, causal);

  k_gemm<1><<<dim3(MTOT / 128, D_ / 128, 1), 256, 0, stream>>>(
      ao, nullptr, nullptr, wob, nullptr, nullptr, nullptr, out, bo, MTOT, D_, D_);
}